// Round 11
// baseline (542.199 us; speedup 1.0000x reference)
//
#include <hip/hip_runtime.h>
#include <stdint.h>

// ---------------------------------------------------------------------------
// RGNN layer: h_t = relu( sum_k L^{k+1} (x_t W_k + h_{t-1} H_k) ), h_{-1}=0
// B=8 T=16 N=1024 F=128 K=4.
//
//   Lcat [1024 n][4096 q],  q=(k,m):  Lcat[n][k*1024+m] = (L^{k+1})[n][m]
//   S    [(b,g) c][4096 q]          : S[c][q] = (x_t W_k + h H_k)[b,m,g]
//   Z[n][c] = sum_q Lcat[n][q] * S[c][q]
//
// Laws (rounds 4,7,8): LDS staging mandatory (dedup); no in-kernel
// cross-block fences (wbl2 storm); split-K mandatory for L2 residency
// (per-XCD working set < 4MB); 16x16 frags conflict-free w/ XOR swizzle
// (32x32 = structural 4-way). LDS bytes = M*N*K*2*(1/WM+1/WN).
//
// Round 11 (occupancy experiment): graph 64x128 tiles, grid 1024 (3 blk/CU
// -> 3 waves/SIMD, +50% LDS traffic for +50% latency-hiding); chain 64x32
// tiles grid 512 (2 blk/CU, was 1). Feat/combine unchanged.
// ---------------------------------------------------------------------------

typedef __bf16 bf16_t;
typedef __bf16 bf16x4 __attribute__((ext_vector_type(4)));
typedef __bf16 bf16x8 __attribute__((ext_vector_type(8)));
typedef float  f32x4  __attribute__((ext_vector_type(4)));

__device__ __forceinline__ void gload_lds16(const void* g, void* l) {
    __builtin_amdgcn_global_load_lds(
        (const __attribute__((address_space(1))) void*)g,
        (__attribute__((address_space(3))) void*)l,
        16, 0, 0);
}

template<int N> __device__ __forceinline__ void wait_vmcnt() {
    if constexpr (N == 0)       asm volatile("s_waitcnt vmcnt(0)" ::: "memory");
    else if constexpr (N == 2)  asm volatile("s_waitcnt vmcnt(2)" ::: "memory");
    else if constexpr (N == 3)  asm volatile("s_waitcnt vmcnt(3)" ::: "memory");
    else if constexpr (N == 4)  asm volatile("s_waitcnt vmcnt(4)" ::: "memory");
    else if constexpr (N == 6)  asm volatile("s_waitcnt vmcnt(6)" ::: "memory");
    else if constexpr (N == 8)  asm volatile("s_waitcnt vmcnt(8)" ::: "memory");
    else                        asm volatile("s_waitcnt vmcnt(16)" ::: "memory");
}

// ---- setup kernels --------------------------------------------------------

__global__ void k_convert_x(const float* __restrict__ xin,
                            bf16_t* __restrict__ xb, int n4) {
    int i = blockIdx.x * 256 + threadIdx.x;
    int stride = gridDim.x * 256;
    for (; i < n4; i += stride) {
        float4 v = reinterpret_cast<const float4*>(xin)[i];
        bf16x4 o = { (bf16_t)v.x, (bf16_t)v.y, (bf16_t)v.z, (bf16_t)v.w };
        reinterpret_cast<bf16x4*>(xb)[i] = o;
    }
}

__global__ void k_setup_L(const float* __restrict__ L,
                          bf16_t* __restrict__ Lcat,   // [1024][4096], block 0
                          bf16_t* __restrict__ Lt) {   // [1024][1024] = L^T
    int idx = blockIdx.x * 256 + threadIdx.x;          // 1024*1024 threads
    int n = idx >> 10, m = idx & 1023;
    float v = L[idx];
    Lcat[n * 4096 + m] = (bf16_t)v;
    Lt[m * 1024 + n]   = (bf16_t)v;
}

__global__ void k_setup_WH(const float* __restrict__ W,
                           const float* __restrict__ H,
                           bf16_t* __restrict__ WHT) { // [4][128 g][256 f]
    int idx = blockIdx.x * 256 + threadIdx.x;          // 4*128*128 threads
    int k = idx >> 14, f = (idx >> 7) & 127, g = idx & 127;
    WHT[(k * 128 + g) * 256 + f]       = (bf16_t)W[idx];
    WHT[(k * 128 + g) * 256 + 128 + f] = (bf16_t)H[idx];
}

// ---- combine: Z = relu(sum_{z<8} Zp_bf16[z]) -> h bf16, out f32 ------------

__global__ __launch_bounds__(256)
void k_combine8(const bf16_t* __restrict__ Zp,  // [8][1024][1024] (n, c=(b,g))
                bf16_t* __restrict__ h, float* __restrict__ out, int t) {
    int i = blockIdx.x * 256 + threadIdx.x;     // 131072 threads, 8 vals each
    int n  = i >> 7;
    int c8 = (i & 127) * 8;
    size_t o = (size_t)n * 1024 + c8;
    float s[8] = {};
    #pragma unroll
    for (int z = 0; z < 8; ++z) {
        bf16x8 v = *reinterpret_cast<const bf16x8*>(Zp + (size_t)z * 1048576 + o);
        #pragma unroll
        for (int j = 0; j < 8; ++j) s[j] += (float)v[j];
    }
    bf16x8 hb;
    float4 o0, o1;
    #pragma unroll
    for (int j = 0; j < 8; ++j) {
        s[j] = fmaxf(s[j], 0.f);
        hb[j] = (bf16_t)s[j];
    }
    o0.x = s[0]; o0.y = s[1]; o0.z = s[2]; o0.w = s[3];
    o1.x = s[4]; o1.y = s[5]; o1.z = s[6]; o1.w = s[7];
    int b = c8 >> 7, g = c8 & 127;
    *reinterpret_cast<bf16x8*>(h + (size_t)b * 131072 + (size_t)n * 128 + g) = hb;
    float* op = out + (size_t)b * 2097152 + (size_t)t * 131072
                    + (size_t)n * 128 + g;
    *reinterpret_cast<float4*>(op)     = o0;
    *reinterpret_cast<float4*>(op + 4) = o1;
}

// ---- GEMM body (16x16x32 MFMA, counted-vmcnt pipeline, NBUF=2 or 3) --------
// C[M][N] = A[M][KTOT] @ B[KTOT][N], B given as B^T rows (N rows, K contig).
// 4 waves 2x2, wave tile (BM/2)x(BN/2), 16x16 fragments (conflict-free with
// the XOR swizzle). Grid 1D, bijective XCD swizzle; DEC=0: x fast / z slow;
// DEC=1: (y,z) fast / x slow.
// EPI: 0 plain bf16   1 S-layout bf16   2 relu h+out   3 bf16 partial Zp[bz]
// BADDR: 0 = BT rows; 1 = feature split x|h.   ZK: per-bz K offset.
template<int BM, int BN, int GX, int GY, int GZ, int KTOT,
         int EPI, int BADDR, int ZK, int DEC, int NBUF>
__device__ __forceinline__
void gemm_body(const bf16_t* __restrict__ A, int lda,
               const bf16_t* __restrict__ BT, int ldbt,
               const bf16_t* __restrict__ B2,
               bf16_t* __restrict__ Cb, float* __restrict__ Cf,
               int ldc, int t)
{
    constexpr int BK = 64;                 // K-tile; LDS rows are 128 B
    constexpr int WM = BM / 2, WN = BN / 2;
    constexpr int MF = WM / 16, NF = WN / 16;
    constexpr int NT = KTOT / BK;
    constexpr int NWG = GX * GY * GZ;
    constexpr int ACH = BM * 8;            // 16B chunks per A tile
    constexpr int BCH = BN * 8;
    constexpr int LPT = (ACH + BCH) / 256; // gloads per thread per tile

    __shared__ __align__(16) bf16_t As[NBUF][BM * BK];
    __shared__ __align__(16) bf16_t Bs[NBUF][BN * BK];

    const int tid  = threadIdx.x;
    const int lane = tid & 63;
    const int wave = tid >> 6;
    const int wm = wave >> 1, wn = wave & 1;     // 2x2 wave grid

    // bijective XCD swizzle (NWG % 8 == 0)
    const int id  = blockIdx.x;
    const int swz = (id & 7) * (NWG / 8) + (id >> 3);
    int bx, by, bz;
    if (DEC == 0) {
        bx = swz % GX; by = (swz / GX) % GY; bz = swz / (GX * GY);
    } else {
        by = swz % GY; bz = (swz / GY) % GZ; bx = swz / (GY * GZ);
    }

    const int m0 = by * BM;
    const int c0 = bx * BN;
    const int kb_ = bz;                          // tap index OR split-K slice

    const bf16_t* Ap = (EPI == 1) ? (A + kb_ * 128 * 256) : A;

    f32x4 acc[MF][NF] = {};

    auto stage = [&](int bufi, int kt) {
        const int q0 = kt * BK + (ZK > 0 ? kb_ * ZK : 0);
        #pragma unroll
        for (int i = 0; i < ACH / 256; ++i) {
            int chunk = i * 256 + tid;
            int off = chunk * 16;                       // byte off in tile
            int row = off >> 7;                         // 128B rows
            int kel = ((off ^ ((row & 7) << 4)) & 127) >> 1; // inv-swizzled k
            const bf16_t* src = Ap + (size_t)(m0 + row) * lda + (q0 + kel);
            gload_lds16(src, (char*)(&As[bufi][0]) + off);
        }
        #pragma unroll
        for (int i = 0; i < BCH / 256; ++i) {
            int chunk = i * 256 + tid;
            int off = chunk * 16;
            int row = off >> 7;
            int kel = ((off ^ ((row & 7) << 4)) & 127) >> 1;
            int c = c0 + row;
            const bf16_t* src;
            if (BADDR == 0) {
                src = BT + (size_t)c * ldbt + (q0 + kel);
            } else {
                int f = q0 + kel;
                if (q0 < 128) {
                    // x part: xb[B][T][N][F], c=(b,m)
                    src = BT + (size_t)(c >> 10) * 2097152
                             + (size_t)t * 131072
                             + (size_t)(c & 1023) * 128 + f;
                } else {
                    // h part: h[B][N][F] flat, rows are c
                    src = B2 + (size_t)c * 128 + (f - 128);
                }
            }
            gload_lds16(src, (char*)(&Bs[bufi][0]) + off);
        }
    };

    auto compute = [&](int cur) {
        #pragma unroll
        for (int kk = 0; kk < 2; ++kk) {
            bf16x8 af[MF], bfr[NF];
            const int klane = (kk * 32 + (lane >> 4) * 8) * 2; // byte off of k
            #pragma unroll
            for (int mf = 0; mf < MF; ++mf) {
                int row = wm * WM + mf * 16 + (lane & 15);
                int bo = (row * 128 + klane) ^ ((row & 7) << 4);
                af[mf] = *reinterpret_cast<const bf16x8*>(
                             (const char*)(&As[cur][0]) + bo);
            }
            #pragma unroll
            for (int nf = 0; nf < NF; ++nf) {
                int row = wn * WN + nf * 16 + (lane & 15);
                int bo = (row * 128 + klane) ^ ((row & 7) << 4);
                bfr[nf] = *reinterpret_cast<const bf16x8*>(
                              (const char*)(&Bs[cur][0]) + bo);
            }
            #pragma unroll
            for (int mf = 0; mf < MF; ++mf)
                #pragma unroll
                for (int nf = 0; nf < NF; ++nf)
                    acc[mf][nf] = __builtin_amdgcn_mfma_f32_16x16x32_bf16(
                        af[mf], bfr[nf], acc[mf][nf], 0, 0, 0);
        }
    };

    if constexpr (NBUF == 3) {
        // 3-buffer, 1 barrier/tile
        stage(0, 0);
        stage(1, 1);
        for (int kt = 0; kt < NT; ++kt) {
            if (kt < NT - 1) wait_vmcnt<LPT>(); else wait_vmcnt<0>();
            __builtin_amdgcn_s_barrier();
            __builtin_amdgcn_sched_barrier(0);
            if (kt + 2 < NT) stage((kt + 2) % 3, kt + 2);
            compute(kt % 3);
            __builtin_amdgcn_sched_barrier(0);
        }
    } else {
        // 2-buffer, both tiles prologue-staged; in-loop stage before the
        // counted wait (loads span the barrier; never vmcnt(0) mid-loop).
        stage(0, 0);
        stage(1, 1);
        for (int kt = 0; kt < NT; ++kt) {
            if (kt > 0 && kt + 1 < NT) {
                __builtin_amdgcn_s_barrier();   // readers of buf[(kt+1)&1] done
                stage((kt + 1) & 1, kt + 1);
            }
            if (kt + 1 < NT) wait_vmcnt<LPT>(); // tile kt done; kt+1 in flight
            else             wait_vmcnt<0>();
            __builtin_amdgcn_s_barrier();       // tile kt visible to all waves
            __builtin_amdgcn_sched_barrier(0);
            compute(kt & 1);
            __builtin_amdgcn_sched_barrier(0);
        }
    }

    // epilogue: 16x16 D map col=lane&15, row=(lane>>4)*4+r  [m89-verified]
    #pragma unroll
    for (int mf = 0; mf < MF; ++mf) {
        #pragma unroll
        for (int nf = 0; nf < NF; ++nf) {
            f32x4 v = acc[mf][nf];
            int col   = c0 + wn * WN + nf * 16 + (lane & 15);
            int rbase = m0 + wm * WM + mf * 16 + ((lane >> 4) * 4);
            #pragma unroll
            for (int r = 0; r < 4; ++r) {
                int row = rbase + r;
                float val = v[r];
                if (EPI == 0) {
                    Cb[(size_t)row * ldc + col] = (bf16_t)val;
                } else if (EPI == 1) {
                    // S[b][g][k][m]: col=(b,m), row=g
                    Cb[(size_t)(col >> 10) * 524288 + (size_t)row * 4096
                       + (size_t)kb_ * 1024 + (col & 1023)] = (bf16_t)val;
                } else if (EPI == 2) {
                    val = fmaxf(val, 0.f);
                    int b = col >> 7, g = col & 127;   // col=(b,g), row=n
                    Cb[(size_t)b * 131072 + (size_t)row * 128 + g] = (bf16_t)val;
                    Cf[(size_t)b * 2097152 + (size_t)t * 131072
                       + (size_t)row * 128 + g] = val;
                } else {
                    // bf16 partial: Zp[kb_][row n][col c]
                    Cb[(size_t)kb_ * 1048576 + (size_t)row * 1024 + col]
                        = (bf16_t)val;
                }
            }
        }
    }
}

// ---- flavor wrappers (distinct symbols for rocprof) ------------------------

__global__ __launch_bounds__(256)
void k_chain(const bf16_t* __restrict__ A, const bf16_t* __restrict__ BT,
             bf16_t* __restrict__ Cb) {
    // M=N=K=1024, 64x32 tiles, grid 512 (2 blk/CU), 3-buf, LPT=3
    gemm_body<64, 32, 32, 16, 1, 1024, 0, 0, 0, 0, 3>(
        A, 4096, BT, 1024, nullptr, Cb, nullptr, 4096, 0);
}

__global__ __launch_bounds__(256)
void k_feat(const bf16_t* __restrict__ WHT, const bf16_t* __restrict__ xb,
            const bf16_t* __restrict__ h, bf16_t* __restrict__ Sbuf, int t) {
    // M=128,N=8192,K=256 per tap; 128x64 tiles, grid 128*1*4 = 512, 3-buf
    gemm_body<128, 64, 128, 1, 4, 256, 1, 1, 0, 1, 3>(
        WHT, 256, xb, 0, h, Sbuf, nullptr, 0, t);
}

__global__ __launch_bounds__(256)
void k_graph(const bf16_t* __restrict__ Lcat, const bf16_t* __restrict__ Sbuf,
             bf16_t* __restrict__ Zp) {
    // M=1024,N=1024, split-K=8 (K=512/slice, one slice per XCD);
    // 64x128 tiles, grid 8*16*8 = 1024 (3 blk/CU resident), 2-buf,
    // bf16 partials
    gemm_body<64, 128, 8, 16, 8, 512, 3, 0, 512, 0, 2>(
        Lcat, 4096, Sbuf, 4096, nullptr, Zp, nullptr, 0, 0);
}

__global__ __launch_bounds__(256)
void k_graph_ns(const bf16_t* __restrict__ Lcat, const bf16_t* __restrict__ Sbuf,
                bf16_t* __restrict__ h, float* __restrict__ out, int t) {
    // fallback: no split-K, K=4096; 128x128 tiles, grid 64, 3-buf
    gemm_body<128, 128, 8, 8, 1, 4096, 2, 0, 0, 0, 3>(
        Lcat, 4096, Sbuf, 4096, nullptr, h, out, 0, t);
}

// ---- launch ---------------------------------------------------------------

extern "C" void kernel_launch(void* const* d_in, const int* in_sizes, int n_in,
                              void* d_out, int out_size, void* d_ws, size_t ws_size,
                              hipStream_t stream) {
    const float* x = (const float*)d_in[0];   // [8][16][1024][128]
    const float* L = (const float*)d_in[1];   // [1024][1024]
    const float* W = (const float*)d_in[2];   // [4][128][128]
    const float* H = (const float*)d_in[3];   // [4][128][128]
    float* out = (float*)d_out;               // [8][16][1024][128]

    char* ws = (char*)d_ws;
    bf16_t* xb   = (bf16_t*)(ws);              // 33,554,432 B
    bf16_t* Lcat = (bf16_t*)(ws + 33554432);   //  8,388,608 B [1024][4096]
    bf16_t* Lt   = (bf16_t*)(ws + 41943040);   //  2,097,152 B
    bf16_t* WHT  = (bf16_t*)(ws + 44040192);   //    262,144 B
    bf16_t* Sbuf = (bf16_t*)(ws + 44302336);   //  8,388,608 B [1024][4096]
    bf16_t* h    = (bf16_t*)(ws + 52690944);   //  2,097,152 B [8][1024][128]
    bf16_t* Zp   = (bf16_t*)(ws + 54788096);   // 16,777,216 B [8][1024][1024]
    if (ws_size < 54788096u) return;
    const bool bigws = (ws_size >= 71565312u);

    hipMemsetAsync(h, 0, 2097152, stream);
    k_convert_x<<<4096, 256, 0, stream>>>(x, xb, 16777216 / 4);
    k_setup_L <<<4096, 256, 0, stream>>>(L, Lcat, Lt);
    k_setup_WH<<<256, 256, 0, stream>>>(W, H, WHT);

    // L-power chain: block p = block(p-1) @ L (M=N=K=1024), 512 WGs each
    for (int p = 1; p < 4; ++p) {
        k_chain<<<512, 256, 0, stream>>>(Lcat + (p - 1) * 1024, Lt,
                                         Lcat + p * 1024);
    }

    for (int t = 0; t < 16; ++t) {
        // feature: S_k = WHT_k @ [x_t | h]^T  (M=128,N=8192,K=256), 512 WGs
        k_feat<<<512, 256, 0, stream>>>(WHT, xb, h, Sbuf, t);
        if (bigws) {
            // graph: Zp[z] = Lcat[:,z*512:+512] @ S[z], split-K=8, 1024 WGs
            k_graph<<<1024, 256, 0, stream>>>(Lcat, Sbuf, Zp);
            k_combine8<<<512, 256, 0, stream>>>(Zp, h, out, t);
        } else {
            k_graph_ns<<<64, 256, 0, stream>>>(Lcat, Sbuf, h, out, t);
        }
    }
}

// Round 12
// 502.561 us; speedup vs baseline: 1.0789x; 1.0789x over previous
//
#include <hip/hip_runtime.h>
#include <stdint.h>

// ---------------------------------------------------------------------------
// RGNN layer: h_t = relu( sum_k L^{k+1} (x_t W_k + h_{t-1} H_k) ), h_{-1}=0
// B=8 T=16 N=1024 F=128 K=4.
//
//   Lcat [1024 n][4096 q],  q=(k,m):  Lcat[n][k*1024+m] = (L^{k+1})[n][m]
//   S    [(b,g) c][4096 q]          : S[c][q] = (x_t W_k + h H_k)[b,m,g]
//   Z[n][c] = sum_q Lcat[n][q] * S[c][q]
//
// Laws (rounds 4,7,8,11): LDS staging mandatory (dedup); no in-kernel
// cross-block fences (wbl2 storm); split-K mandatory for L2 residency
// (per-XCD working set < 4MB); 16x16 frags conflict-free w/ XOR swizzle
// (32x32 = structural 4-way); GEMM time tracks LDS traffic
// M*N*K*2*(1/WM+1/WN) -> 64x64 wave tiles @ 2 blk/CU is the local optimum
// (round-11: 3 blk/CU with +50% LDS traffic REGRESSED).
//
// Round 12: revert to round-10 geometry (graph 128^2 split-K=8 NBUF=2,
// chain 64^2 grid 256). NEW: compute() loads all fragments first, then a
// pure-MFMA cluster wrapped in s_setprio(1/0) (T5) — the 2 resident blocks
// per CU are at different K-phases, giving the scheduler roles to arbitrate.
// ---------------------------------------------------------------------------

typedef __bf16 bf16_t;
typedef __bf16 bf16x4 __attribute__((ext_vector_type(4)));
typedef __bf16 bf16x8 __attribute__((ext_vector_type(8)));
typedef float  f32x4  __attribute__((ext_vector_type(4)));

__device__ __forceinline__ void gload_lds16(const void* g, void* l) {
    __builtin_amdgcn_global_load_lds(
        (const __attribute__((address_space(1))) void*)g,
        (__attribute__((address_space(3))) void*)l,
        16, 0, 0);
}

template<int N> __device__ __forceinline__ void wait_vmcnt() {
    if constexpr (N == 0)       asm volatile("s_waitcnt vmcnt(0)" ::: "memory");
    else if constexpr (N == 2)  asm volatile("s_waitcnt vmcnt(2)" ::: "memory");
    else if constexpr (N == 3)  asm volatile("s_waitcnt vmcnt(3)" ::: "memory");
    else if constexpr (N == 4)  asm volatile("s_waitcnt vmcnt(4)" ::: "memory");
    else if constexpr (N == 6)  asm volatile("s_waitcnt vmcnt(6)" ::: "memory");
    else if constexpr (N == 8)  asm volatile("s_waitcnt vmcnt(8)" ::: "memory");
    else                        asm volatile("s_waitcnt vmcnt(16)" ::: "memory");
}

// ---- setup kernels --------------------------------------------------------

__global__ void k_convert_x(const float* __restrict__ xin,
                            bf16_t* __restrict__ xb, int n4) {
    int i = blockIdx.x * 256 + threadIdx.x;
    int stride = gridDim.x * 256;
    for (; i < n4; i += stride) {
        float4 v = reinterpret_cast<const float4*>(xin)[i];
        bf16x4 o = { (bf16_t)v.x, (bf16_t)v.y, (bf16_t)v.z, (bf16_t)v.w };
        reinterpret_cast<bf16x4*>(xb)[i] = o;
    }
}

__global__ void k_setup_L(const float* __restrict__ L,
                          bf16_t* __restrict__ Lcat,   // [1024][4096], block 0
                          bf16_t* __restrict__ Lt) {   // [1024][1024] = L^T
    int idx = blockIdx.x * 256 + threadIdx.x;          // 1024*1024 threads
    int n = idx >> 10, m = idx & 1023;
    float v = L[idx];
    Lcat[n * 4096 + m] = (bf16_t)v;
    Lt[m * 1024 + n]   = (bf16_t)v;
}

__global__ void k_setup_WH(const float* __restrict__ W,
                           const float* __restrict__ H,
                           bf16_t* __restrict__ WHT) { // [4][128 g][256 f]
    int idx = blockIdx.x * 256 + threadIdx.x;          // 4*128*128 threads
    int k = idx >> 14, f = (idx >> 7) & 127, g = idx & 127;
    WHT[(k * 128 + g) * 256 + f]       = (bf16_t)W[idx];
    WHT[(k * 128 + g) * 256 + 128 + f] = (bf16_t)H[idx];
}

// ---- combine: Z = relu(sum_{z<8} Zp_bf16[z]) -> h bf16, out f32 ------------

__global__ __launch_bounds__(256)
void k_combine8(const bf16_t* __restrict__ Zp,  // [8][1024][1024] (n, c=(b,g))
                bf16_t* __restrict__ h, float* __restrict__ out, int t) {
    int i = blockIdx.x * 256 + threadIdx.x;     // 131072 threads, 8 vals each
    int n  = i >> 7;
    int c8 = (i & 127) * 8;
    size_t o = (size_t)n * 1024 + c8;
    float s[8] = {};
    #pragma unroll
    for (int z = 0; z < 8; ++z) {
        bf16x8 v = *reinterpret_cast<const bf16x8*>(Zp + (size_t)z * 1048576 + o);
        #pragma unroll
        for (int j = 0; j < 8; ++j) s[j] += (float)v[j];
    }
    bf16x8 hb;
    float4 o0, o1;
    #pragma unroll
    for (int j = 0; j < 8; ++j) {
        s[j] = fmaxf(s[j], 0.f);
        hb[j] = (bf16_t)s[j];
    }
    o0.x = s[0]; o0.y = s[1]; o0.z = s[2]; o0.w = s[3];
    o1.x = s[4]; o1.y = s[5]; o1.z = s[6]; o1.w = s[7];
    int b = c8 >> 7, g = c8 & 127;
    *reinterpret_cast<bf16x8*>(h + (size_t)b * 131072 + (size_t)n * 128 + g) = hb;
    float* op = out + (size_t)b * 2097152 + (size_t)t * 131072
                    + (size_t)n * 128 + g;
    *reinterpret_cast<float4*>(op)     = o0;
    *reinterpret_cast<float4*>(op + 4) = o1;
}

// ---- GEMM body (16x16x32 MFMA, counted-vmcnt pipeline, NBUF=2 or 3) --------
// C[M][N] = A[M][KTOT] @ B[KTOT][N], B given as B^T rows (N rows, K contig).
// 4 waves 2x2, wave tile (BM/2)x(BN/2), 16x16 fragments (conflict-free with
// the XOR swizzle). Grid 1D, bijective XCD swizzle; DEC=0: x fast / z slow;
// DEC=1: (y,z) fast / x slow.
// EPI: 0 plain bf16   1 S-layout bf16   2 relu h+out   3 bf16 partial Zp[bz]
// BADDR: 0 = BT rows; 1 = feature split x|h.   ZK: per-bz K offset.
template<int BM, int BN, int GX, int GY, int GZ, int KTOT,
         int EPI, int BADDR, int ZK, int DEC, int NBUF>
__device__ __forceinline__
void gemm_body(const bf16_t* __restrict__ A, int lda,
               const bf16_t* __restrict__ BT, int ldbt,
               const bf16_t* __restrict__ B2,
               bf16_t* __restrict__ Cb, float* __restrict__ Cf,
               int ldc, int t)
{
    constexpr int BK = 64;                 // K-tile; LDS rows are 128 B
    constexpr int WM = BM / 2, WN = BN / 2;
    constexpr int MF = WM / 16, NF = WN / 16;
    constexpr int NT = KTOT / BK;
    constexpr int NWG = GX * GY * GZ;
    constexpr int ACH = BM * 8;            // 16B chunks per A tile
    constexpr int BCH = BN * 8;
    constexpr int LPT = (ACH + BCH) / 256; // gloads per thread per tile

    __shared__ __align__(16) bf16_t As[NBUF][BM * BK];
    __shared__ __align__(16) bf16_t Bs[NBUF][BN * BK];

    const int tid  = threadIdx.x;
    const int lane = tid & 63;
    const int wave = tid >> 6;
    const int wm = wave >> 1, wn = wave & 1;     // 2x2 wave grid

    // bijective XCD swizzle (NWG % 8 == 0)
    const int id  = blockIdx.x;
    const int swz = (id & 7) * (NWG / 8) + (id >> 3);
    int bx, by, bz;
    if (DEC == 0) {
        bx = swz % GX; by = (swz / GX) % GY; bz = swz / (GX * GY);
    } else {
        by = swz % GY; bz = (swz / GY) % GZ; bx = swz / (GY * GZ);
    }

    const int m0 = by * BM;
    const int c0 = bx * BN;
    const int kb_ = bz;                          // tap index OR split-K slice

    const bf16_t* Ap = (EPI == 1) ? (A + kb_ * 128 * 256) : A;

    f32x4 acc[MF][NF] = {};

    auto stage = [&](int bufi, int kt) {
        const int q0 = kt * BK + (ZK > 0 ? kb_ * ZK : 0);
        #pragma unroll
        for (int i = 0; i < ACH / 256; ++i) {
            int chunk = i * 256 + tid;
            int off = chunk * 16;                       // byte off in tile
            int row = off >> 7;                         // 128B rows
            int kel = ((off ^ ((row & 7) << 4)) & 127) >> 1; // inv-swizzled k
            const bf16_t* src = Ap + (size_t)(m0 + row) * lda + (q0 + kel);
            gload_lds16(src, (char*)(&As[bufi][0]) + off);
        }
        #pragma unroll
        for (int i = 0; i < BCH / 256; ++i) {
            int chunk = i * 256 + tid;
            int off = chunk * 16;
            int row = off >> 7;
            int kel = ((off ^ ((row & 7) << 4)) & 127) >> 1;
            int c = c0 + row;
            const bf16_t* src;
            if (BADDR == 0) {
                src = BT + (size_t)c * ldbt + (q0 + kel);
            } else {
                int f = q0 + kel;
                if (q0 < 128) {
                    // x part: xb[B][T][N][F], c=(b,m)
                    src = BT + (size_t)(c >> 10) * 2097152
                             + (size_t)t * 131072
                             + (size_t)(c & 1023) * 128 + f;
                } else {
                    // h part: h[B][N][F] flat, rows are c
                    src = B2 + (size_t)c * 128 + (f - 128);
                }
            }
            gload_lds16(src, (char*)(&Bs[bufi][0]) + off);
        }
    };

    // compute: load ALL fragments (both kk halves) into registers, then a
    // pure-MFMA cluster under setprio(1) (T5 — pays when resident blocks
    // are at different phases; our 2 blk/CU qualify).
    auto compute = [&](int cur) {
        bf16x8 af[2][MF], bfr[2][NF];
        #pragma unroll
        for (int kk = 0; kk < 2; ++kk) {
            const int klane = (kk * 32 + (lane >> 4) * 8) * 2; // byte off of k
            #pragma unroll
            for (int mf = 0; mf < MF; ++mf) {
                int row = wm * WM + mf * 16 + (lane & 15);
                int bo = (row * 128 + klane) ^ ((row & 7) << 4);
                af[kk][mf] = *reinterpret_cast<const bf16x8*>(
                                 (const char*)(&As[cur][0]) + bo);
            }
            #pragma unroll
            for (int nf = 0; nf < NF; ++nf) {
                int row = wn * WN + nf * 16 + (lane & 15);
                int bo = (row * 128 + klane) ^ ((row & 7) << 4);
                bfr[kk][nf] = *reinterpret_cast<const bf16x8*>(
                                  (const char*)(&Bs[cur][0]) + bo);
            }
        }
        __builtin_amdgcn_s_setprio(1);
        #pragma unroll
        for (int kk = 0; kk < 2; ++kk)
            #pragma unroll
            for (int mf = 0; mf < MF; ++mf)
                #pragma unroll
                for (int nf = 0; nf < NF; ++nf)
                    acc[mf][nf] = __builtin_amdgcn_mfma_f32_16x16x32_bf16(
                        af[kk][mf], bfr[kk][nf], acc[mf][nf], 0, 0, 0);
        __builtin_amdgcn_s_setprio(0);
    };

    if constexpr (NBUF == 3) {
        // 3-buffer, 1 barrier/tile
        stage(0, 0);
        stage(1, 1);
        for (int kt = 0; kt < NT; ++kt) {
            if (kt < NT - 1) wait_vmcnt<LPT>(); else wait_vmcnt<0>();
            __builtin_amdgcn_s_barrier();
            __builtin_amdgcn_sched_barrier(0);
            if (kt + 2 < NT) stage((kt + 2) % 3, kt + 2);
            compute(kt % 3);
            __builtin_amdgcn_sched_barrier(0);
        }
    } else {
        // 2-buffer, both tiles prologue-staged; in-loop stage before the
        // counted wait (loads span the barrier; never vmcnt(0) mid-loop).
        stage(0, 0);
        stage(1, 1);
        for (int kt = 0; kt < NT; ++kt) {
            if (kt > 0 && kt + 1 < NT) {
                __builtin_amdgcn_s_barrier();   // readers of buf[(kt+1)&1] done
                stage((kt + 1) & 1, kt + 1);
            }
            if (kt + 1 < NT) wait_vmcnt<LPT>(); // tile kt done; kt+1 in flight
            else             wait_vmcnt<0>();
            __builtin_amdgcn_s_barrier();       // tile kt visible to all waves
            __builtin_amdgcn_sched_barrier(0);
            compute(kt & 1);
            __builtin_amdgcn_sched_barrier(0);
        }
    }

    // epilogue: 16x16 D map col=lane&15, row=(lane>>4)*4+r  [m89-verified]
    #pragma unroll
    for (int mf = 0; mf < MF; ++mf) {
        #pragma unroll
        for (int nf = 0; nf < NF; ++nf) {
            f32x4 v = acc[mf][nf];
            int col   = c0 + wn * WN + nf * 16 + (lane & 15);
            int rbase = m0 + wm * WM + mf * 16 + ((lane >> 4) * 4);
            #pragma unroll
            for (int r = 0; r < 4; ++r) {
                int row = rbase + r;
                float val = v[r];
                if (EPI == 0) {
                    Cb[(size_t)row * ldc + col] = (bf16_t)val;
                } else if (EPI == 1) {
                    // S[b][g][k][m]: col=(b,m), row=g
                    Cb[(size_t)(col >> 10) * 524288 + (size_t)row * 4096
                       + (size_t)kb_ * 1024 + (col & 1023)] = (bf16_t)val;
                } else if (EPI == 2) {
                    val = fmaxf(val, 0.f);
                    int b = col >> 7, g = col & 127;   // col=(b,g), row=n
                    Cb[(size_t)b * 131072 + (size_t)row * 128 + g] = (bf16_t)val;
                    Cf[(size_t)b * 2097152 + (size_t)t * 131072
                       + (size_t)row * 128 + g] = val;
                } else {
                    // bf16 partial: Zp[kb_][row n][col c]
                    Cb[(size_t)kb_ * 1048576 + (size_t)row * 1024 + col]
                        = (bf16_t)val;
                }
            }
        }
    }
}

// ---- flavor wrappers (distinct symbols for rocprof) ------------------------

__global__ __launch_bounds__(256)
void k_chain(const bf16_t* __restrict__ A, const bf16_t* __restrict__ BT,
             bf16_t* __restrict__ Cb) {
    // M=N=K=1024, 64x64 tiles, grid 256, 3-buf
    gemm_body<64, 64, 16, 16, 1, 1024, 0, 0, 0, 0, 3>(
        A, 4096, BT, 1024, nullptr, Cb, nullptr, 4096, 0);
}

__global__ __launch_bounds__(256)
void k_feat(const bf16_t* __restrict__ WHT, const bf16_t* __restrict__ xb,
            const bf16_t* __restrict__ h, bf16_t* __restrict__ Sbuf, int t) {
    // M=128,N=8192,K=256 per tap; 128x64 tiles, grid 128*1*4 = 512, 3-buf
    gemm_body<128, 64, 128, 1, 4, 256, 1, 1, 0, 1, 3>(
        WHT, 256, xb, 0, h, Sbuf, nullptr, 0, t);
}

__global__ __launch_bounds__(256)
void k_graph(const bf16_t* __restrict__ Lcat, const bf16_t* __restrict__ Sbuf,
             bf16_t* __restrict__ Zp) {
    // M=1024,N=1024, split-K=8 (K=512/slice, one slice per XCD);
    // 128x128 tiles / 64x64 waves, grid 512, 2-buf, bf16 partials
    gemm_body<128, 128, 8, 8, 8, 512, 3, 0, 512, 0, 2>(
        Lcat, 4096, Sbuf, 4096, nullptr, Zp, nullptr, 0, 0);
}

__global__ __launch_bounds__(256)
void k_graph_ns(const bf16_t* __restrict__ Lcat, const bf16_t* __restrict__ Sbuf,
                bf16_t* __restrict__ h, float* __restrict__ out, int t) {
    // fallback: no split-K, K=4096; 128x128 tiles, grid 64, 3-buf
    gemm_body<128, 128, 8, 8, 1, 4096, 2, 0, 0, 0, 3>(
        Lcat, 4096, Sbuf, 4096, nullptr, h, out, 0, t);
}

// ---- launch ---------------------------------------------------------------

extern "C" void kernel_launch(void* const* d_in, const int* in_sizes, int n_in,
                              void* d_out, int out_size, void* d_ws, size_t ws_size,
                              hipStream_t stream) {
    const float* x = (const float*)d_in[0];   // [8][16][1024][128]
    const float* L = (const float*)d_in[1];   // [1024][1024]
    const float* W = (const float*)d_in[2];   // [4][128][128]
    const float* H = (const float*)d_in[3];   // [4][128][128]
    float* out = (float*)d_out;               // [8][16][1024][128]

    char* ws = (char*)d_ws;
    bf16_t* xb   = (bf16_t*)(ws);              // 33,554,432 B
    bf16_t* Lcat = (bf16_t*)(ws + 33554432);   //  8,388,608 B [1024][4096]
    bf16_t* Lt   = (bf16_t*)(ws + 41943040);   //  2,097,152 B
    bf16_t* WHT  = (bf16_t*)(ws + 44040192);   //    262,144 B
    bf16_t* Sbuf = (bf16_t*)(ws + 44302336);   //  8,388,608 B [1024][4096]
    bf16_t* h    = (bf16_t*)(ws + 52690944);   //  2,097,152 B [8][1024][128]
    bf16_t* Zp   = (bf16_t*)(ws + 54788096);   // 16,777,216 B [8][1024][1024]
    if (ws_size < 54788096u) return;
    const bool bigws = (ws_size >= 71565312u);

    hipMemsetAsync(h, 0, 2097152, stream);
    k_convert_x<<<4096, 256, 0, stream>>>(x, xb, 16777216 / 4);
    k_setup_L <<<4096, 256, 0, stream>>>(L, Lcat, Lt);
    k_setup_WH<<<256, 256, 0, stream>>>(W, H, WHT);

    // L-power chain: block p = block(p-1) @ L (M=N=K=1024), 256 WGs
    for (int p = 1; p < 4; ++p) {
        k_chain<<<256, 256, 0, stream>>>(Lcat + (p - 1) * 1024, Lt,
                                         Lcat + p * 1024);
    }

    for (int t = 0; t < 16; ++t) {
        // feature: S_k = WHT_k @ [x_t | h]^T  (M=128,N=8192,K=256), 512 WGs
        k_feat<<<512, 256, 0, stream>>>(WHT, xb, h, Sbuf, t);
        if (bigws) {
            // graph: Zp[z] = Lcat[:,z*512:+512] @ S[z], split-K=8, 512 WGs
            k_graph<<<512, 256, 0, stream>>>(Lcat, Sbuf, Zp);
            k_combine8<<<512, 256, 0, stream>>>(Zp, h, out, t);
        } else {
            k_graph_ns<<<64, 256, 0, stream>>>(Lcat, Sbuf, h, out, t);
        }
    }
}